// Round 10
// baseline (128.725 us; speedup 1.0000x reference)
//
#include <hip/hip_runtime.h>
#include <stdint.h>

// ProbSparse attention (Informer): B=4, L=2048, H=8, D=64, factor=5 -> U_part=u=40.
// out = broadcast mean(V) except top-40 rows per (b,h) get softmax(Q K^T/8) V.
// Row selection is bit-exact jax.random.randint(key(42),(2048,40),0,2048)
// under jax_threefry_partitionable=True (verified passing).
//
// R9 post-mortem: k_M floor = random 256B L2 gather (warm-replay still 45us at
// 5.8 GB/s HBM); attn_part = 1 wave/SIMD, no latency hiding. R10: k_M waves per
// (b,q) computing all 8 heads from the contiguous 2KB row K[b,kk,:,:] (coalesced
// gather, 8x fewer waves); attn_part split u into 4 tiles (4096 blocks, 4 waves/SIMD,
// shuffle-reduce softmax).

static constexpr int Bc = 4, Lc = 2048, Hc = 8, Dc = 64, NUc = 40;
static constexpr int NCH = 32, CHK = 64;  // key chunks for attention
static constexpr int UT = 10;             // queries per attn_part block (4 tiles)

struct TF2 { uint32_t a, b; };

__host__ __device__ constexpr uint32_t rotl32c(uint32_t x, int r) {
    return (x << r) | (x >> (32 - r));
}

// Threefry-2x32, 20 rounds (jax._src.prng.threefry2x32), constexpr-foldable.
__host__ __device__ constexpr TF2 tf2x32c(uint32_t k0, uint32_t k1, uint32_t x0, uint32_t x1) {
    uint32_t ks[3] = {k0, k1, k0 ^ k1 ^ 0x1BD11BDAu};
    const int R0[4] = {13, 15, 26, 6};
    const int R1[4] = {17, 29, 16, 24};
    x0 += ks[0];
    x1 += ks[1];
    for (int i = 0; i < 5; ++i) {
        const int* R = (i & 1) ? R1 : R0;
        for (int j = 0; j < 4; ++j) {
            x0 += x1;
            x1 = rotl32c(x1, R[j]);
            x1 ^= x0;
        }
        x0 += ks[(i + 1) % 3];
        x1 += ks[(i + 2) % 3] + (uint32_t)(i + 1);
    }
    return TF2{x0, x1};
}

// ---------------- k_index: sample indices, computed once ------------------------
__global__ __launch_bounds__(256) void k_index(int* __restrict__ idx) {
    constexpr TF2 K2 = tf2x32c(0u, 42u, 0u, 1u);  // second key of split(key(42))
    int j = blockIdx.x * 256 + threadIdx.x;       // < 81920
    TF2 r = tf2x32c(K2.a, K2.b, 0u, (uint32_t)j);
    idx[j] = (int)((r.a ^ r.b) & 2047u);
}

// ---------------- k_M: sampled sparsity measure, all 8 heads per wave -----------
// Wave per (b,q). Lane l holds flat floats [8l..8l+7] of the 512-float row
// (h = l>>3, dims 8(l&7)..): K[b,kk,:,:] is contiguous 2KB -> both loads fully
// coalesced. 3-stage reduce within the 8-lane head group gives per-head dots;
// no cross-group combine. 8 parallel accumulators break the mx/sm serial chain.
__global__ __launch_bounds__(256, 4) void k_M(const float* __restrict__ Q,
                                              const float* __restrict__ K,
                                              const int* __restrict__ idxg,
                                              float* __restrict__ M) {
    int lane = threadIdx.x & 63;
    int w = threadIdx.x >> 6;
    int blk = blockIdx.x;           // 2048 blocks
    int xcd = blk & 7;              // XCD owns half the q's of one b
    int local = blk >> 3;           // 0..255
    int b = xcd >> 1;
    int q = (xcd & 1) * 1024 + local * 4 + w;
    int h = lane >> 3;
    int myidx = (lane < 40) ? idxg[q * 40 + lane] : 0;

    const float4* Q4 = reinterpret_cast<const float4*>(Q);
    const float4* K4 = reinterpret_cast<const float4*>(K);
    size_t qb = (size_t)(b * Lc + q) * 128;  // float4 slots per (b,l) row
    float4 qv0 = Q4[qb + 2 * lane];
    float4 qv1 = Q4[qb + 2 * lane + 1];

    float mx8[8], sm8[8];
#pragma unroll
    for (int j = 0; j < 8; ++j) { mx8[j] = -INFINITY; sm8[j] = 0.f; }
#pragma unroll
    for (int i = 0; i < 5; ++i) {
#pragma unroll
        for (int j = 0; j < 8; ++j) {
            int kk = __shfl(myidx, i * 8 + j, 64);
            size_t rb = (size_t)(b * Lc + kk) * 128;
            float4 kv0 = K4[rb + 2 * lane];
            float4 kv1 = K4[rb + 2 * lane + 1];
            float pv = qv0.x * kv0.x + qv0.y * kv0.y + qv0.z * kv0.z + qv0.w * kv0.w +
                       qv1.x * kv1.x + qv1.y * kv1.y + qv1.z * kv1.z + qv1.w * kv1.w;
#pragma unroll
            for (int m = 1; m < 8; m <<= 1) pv += __shfl_xor(pv, m, 64);
            mx8[j] = fmaxf(mx8[j], pv);
            sm8[j] += pv;
        }
    }
    float mx = mx8[0], sm = sm8[0];
#pragma unroll
    for (int j = 1; j < 8; ++j) { mx = fmaxf(mx, mx8[j]); sm += sm8[j]; }
    if ((lane & 7) == 0) M[(b * 8 + h) * Lc + q] = mx - sm * (1.0f / 2048.0f);
}

// ---------------- k_topk: register-resident iterative argmax (ties -> smaller idx) --
// Also emits a 2048-bit membership bitmap per (b,h) for the fused output kernel.
__global__ __launch_bounds__(256) void k_topk(const float* __restrict__ M, int* __restrict__ top,
                                              uint32_t* __restrict__ gmask) {
    __shared__ float wvs[4];
    __shared__ int wis[4];
    __shared__ int sel[NUc];
    int bh = blockIdx.x;
    int t = threadIdx.x, lane = t & 63, w = t >> 6;
    float v[8];
#pragma unroll
    for (int i = 0; i < 8; ++i) v[i] = M[bh * Lc + i * 256 + t];
    float bv;
    int bi;
    auto recompute = [&]() {
        bv = v[0];
        bi = t;
#pragma unroll
        for (int i = 1; i < 8; ++i)
            if (v[i] > bv) { bv = v[i]; bi = i * 256 + t; }
    };
    recompute();
    for (int it = 0; it < NUc; ++it) {
        float cv = bv;
        int ci = bi;
#pragma unroll
        for (int m = 1; m < 64; m <<= 1) {
            float ov = __shfl_xor(cv, m, 64);
            int oi = __shfl_xor(ci, m, 64);
            if (ov > cv || (ov == cv && oi < ci)) { cv = ov; ci = oi; }
        }
        if (lane == 0) { wvs[w] = cv; wis[w] = ci; }
        __syncthreads();
        float gv = wvs[0];
        int gi = wis[0];
#pragma unroll
        for (int ww = 1; ww < 4; ++ww) {
            float ov = wvs[ww];
            int oi = wis[ww];
            if (ov > gv || (ov == gv && oi < gi)) { gv = ov; gi = oi; }
        }
        if (t == 0) {
            top[bh * NUc + it] = gi;
            sel[it] = gi;
        }
        if ((gi & 255) == t) {  // owner removes and rescans its 8
            v[gi >> 8] = -INFINITY;
            recompute();
        }
        __syncthreads();
    }
    if (t < 64) {
        uint32_t word = 0;
#pragma unroll
        for (int j = 0; j < NUc; ++j) {
            int s = sel[j];
            if ((s >> 5) == t) word |= 1u << (s & 31);
        }
        gmask[bh * 64 + t] = word;
    }
}

// ---------------- attention partials: 1-wave block = (bh, chunk, u-tile) ---------
// 4096 blocks of 64 threads (16 waves/CU). Shuffle-reduce softmax stats.
// u-tiles of a chunk are consecutive on one XCD -> K/V chunk re-reads L2-hit.
__global__ __launch_bounds__(64, 4) void k_attn_part(const float* __restrict__ Q,
                                                     const float* __restrict__ K,
                                                     const float* __restrict__ V,
                                                     const int* __restrict__ top,
                                                     float* __restrict__ wsO,
                                                     float* __restrict__ wsm,
                                                     float* __restrict__ wsl,
                                                     float* __restrict__ vpart) {
    __shared__ float Qs[UT][64];   // 2.5 KB
    __shared__ float pT[64][12];   // 3 KB (key-local, u + pad to float4 rows)
    __shared__ int tqs[UT];
    int blk = blockIdx.x;          // xcd-affine: 8 XCD x 4 bh x 32 chunk x 4 ut
    int xcd = blk & 7, local = blk >> 3;
    int bh = xcd * 4 + (local >> 7);
    int rem = local & 127;
    int chunk = rem >> 2, ut = rem & 3;
    int b = bh >> 3, h = bh & 7;
    int t = threadIdx.x;  // 0..63 (= lane = key-slot = dim)

    if (t < UT) tqs[t] = top[bh * NUc + ut * UT + t];
    __syncthreads();
#pragma unroll
    for (int j = 0; j < UT; ++j)
        Qs[j][t] = Q[(((size_t)(b * Lc + tqs[j])) * Hc + h) * Dc + t];
    __syncthreads();

    // scores: thread t owns key kg = chunk*64 + t; acc[u] = dot(Q[u], K[kg]) / 8
    int kg = chunk * CHK + t;
    const float4* Kr = reinterpret_cast<const float4*>(&K[(((size_t)(b * Lc + kg)) * Hc + h) * Dc]);
    float acc[UT];
#pragma unroll
    for (int u = 0; u < UT; ++u) acc[u] = 0.f;
#pragma unroll
    for (int i = 0; i < 16; ++i) {
        float4 kv = Kr[i];
#pragma unroll
        for (int u = 0; u < UT; ++u) {
            float4 qv = *reinterpret_cast<const float4*>(&Qs[u][i * 4]);
            acc[u] += qv.x * kv.x + qv.y * kv.y + qv.z * kv.z + qv.w * kv.w;
        }
    }
#pragma unroll
    for (int u = 0; u < UT; ++u) acc[u] *= 0.125f;
    // per-u max over the 64 keys via wave butterfly
    float mr[UT];
#pragma unroll
    for (int u = 0; u < UT; ++u) {
        float v = acc[u];
#pragma unroll
        for (int m = 1; m < 64; m <<= 1) v = fmaxf(v, __shfl_xor(v, m, 64));
        mr[u] = v;
    }
    // exp + stage transposed P into LDS
    float pr[UT];
#pragma unroll
    for (int u = 0; u < UT; ++u) {
        pr[u] = __expf(acc[u] - mr[u]);
        pT[t][u] = pr[u];
    }
    // per-u sum via wave butterfly
    float sr[UT];
#pragma unroll
    for (int u = 0; u < UT; ++u) {
        float v = pr[u];
#pragma unroll
        for (int m = 1; m < 64; m <<= 1) v += __shfl_xor(v, m, 64);
        sr[u] = v;
    }
    // write chunk stats (values wave-uniform; lane u writes entry u)
    int sbase = (bh * NCH + chunk) * NUc + ut * UT;
#pragma unroll
    for (int u = 0; u < UT; ++u) {
        if (t == u) {
            wsm[sbase + u] = mr[u];
            wsl[sbase + u] = sr[u];
        }
    }
    __syncthreads();
    // PV over the 64 keys: lane = d, acc[u] = sum_k p[u][k] * V[k][d].
    // Free byproduct (ut==0 only): vs = sum_k V[k][d] for the V-mean output.
#pragma unroll
    for (int u = 0; u < UT; ++u) acc[u] = 0.f;
    float vs = 0.f;
    const float* Vbh = V + ((size_t)b * Lc * Hc + h) * Dc;
    for (int k = 0; k < 64; ++k) {
        float vv = Vbh[(size_t)(chunk * CHK + k) * 512 + t];
        vs += vv;
        float4 pa = *reinterpret_cast<const float4*>(&pT[k][0]);
        float4 pb = *reinterpret_cast<const float4*>(&pT[k][4]);
        float2 pc = *reinterpret_cast<const float2*>(&pT[k][8]);
        acc[0] += pa.x * vv; acc[1] += pa.y * vv; acc[2] += pa.z * vv; acc[3] += pa.w * vv;
        acc[4] += pb.x * vv; acc[5] += pb.y * vv; acc[6] += pb.z * vv; acc[7] += pb.w * vv;
        acc[8] += pc.x * vv; acc[9] += pc.y * vv;
    }
    if (ut == 0) vpart[(bh * NCH + chunk) * 64 + t] = vs;
    size_t obase = (size_t)(bh * NCH + chunk) * 2560 + (size_t)(ut * UT) * 64;
#pragma unroll
    for (int u = 0; u < UT; ++u) wsO[obase + u * 64 + t] = acc[u];
}

// ---------------- combine 32 chunk-partials -> staged rows + finish V-mean -------
// grid = 32 bh x 8 u-tiles (5 u each) = 256 blocks.
__global__ __launch_bounds__(256) void k_attn_comb(const float* __restrict__ wsO,
                                                   const float* __restrict__ wsm,
                                                   const float* __restrict__ wsl,
                                                   const float* __restrict__ vpart,
                                                   float* __restrict__ stage,
                                                   float* __restrict__ vm) {
    __shared__ float cm[NCH][5], cl[NCH][5], cf[NCH][5];
    int blk = blockIdx.x;  // bh*8 + ut
    int ut = blk & 7, bh = blk >> 3;
    int t = threadIdx.x;
    for (int i = t; i < NCH * 5; i += 256) {
        int c = i / 5, j = i % 5;
        cm[c][j] = wsm[(bh * NCH + c) * NUc + ut * 5 + j];
        cl[c][j] = wsl[(bh * NCH + c) * NUc + ut * 5 + j];
    }
    __syncthreads();
    if (t < 5) {
        float m = -INFINITY;
#pragma unroll
        for (int c = 0; c < NCH; ++c) m = fmaxf(m, cm[c][t]);
        float L = 0.f;
#pragma unroll
        for (int c = 0; c < NCH; ++c) {
            float f = __expf(cm[c][t] - m);
            L += cl[c][t] * f;
            cf[c][t] = f;
        }
        float inv = 1.0f / L;
#pragma unroll
        for (int c = 0; c < NCH; ++c) cf[c][t] *= inv;
    }
    if (ut == 0 && t >= 64 && t < 128) {  // finish V-mean once per bh
        int d = t - 64;
        float s = 0.f;
#pragma unroll
        for (int c = 0; c < NCH; ++c) s += vpart[(bh * NCH + c) * 64 + d];
        vm[bh * 64 + d] = s * (1.0f / 2048.0f);
    }
    __syncthreads();
    for (int i = t; i < 5 * 64; i += 256) {
        int j = i >> 6, d = i & 63;
        float val = 0.f;
#pragma unroll
        for (int c = 0; c < NCH; ++c)
            val += wsO[((size_t)(bh * NCH + c)) * 2560 + (ut * 5 + j) * 64 + d] * cf[c][j];
        stage[(size_t)bh * 2560 + (ut * 5 + j) * 64 + d] = val;
    }
}

// ---------------- fused output: vmean fill + attended-row scatter ----------------
__global__ void k_out(const float* __restrict__ stage, const float* __restrict__ vm,
                      const int* __restrict__ top, const uint32_t* __restrict__ gmask,
                      float* __restrict__ out) {
    int o4 = blockIdx.x * blockDim.x + threadIdx.x;  // over 1M float4
    if (o4 >= Bc * Lc * Hc * (Dc / 4)) return;
    int dq = o4 & 15;
    int h = (o4 >> 4) & 7;
    int bl = o4 >> 7;  // b*2048 + l
    int b = bl >> 11, l = bl & 2047;
    int bh = b * 8 + h;
    float4 v;
    uint32_t wmask = gmask[bh * 64 + (l >> 5)];
    if ((wmask >> (l & 31)) & 1u) {
        int u = 0;
#pragma unroll
        for (int j = 0; j < NUc; ++j)
            if (top[bh * NUc + j] == l) u = j;
        v = reinterpret_cast<const float4*>(stage)[(bh * NUc + u) * 16 + dq];
    } else {
        v = reinterpret_cast<const float4*>(vm)[bh * 16 + dq];
    }
    reinterpret_cast<float4*>(out)[o4] = v;
}

extern "C" void kernel_launch(void* const* d_in, const int* in_sizes, int n_in,
                              void* d_out, int out_size, void* d_ws, size_t ws_size,
                              hipStream_t stream) {
    (void)in_sizes; (void)n_in; (void)out_size; (void)ws_size;
    const float* Q = (const float*)d_in[0];
    const float* K = (const float*)d_in[1];
    const float* V = (const float*)d_in[2];
    float* out = (float*)d_out;

    // d_out-as-scratch (16.78 MB; all consumed before k_out overwrites it):
    float* wsO   = (float*)d_out;                          // 0 .. 10.49 MB
    float* wsm   = (float*)((char*)d_out + 10485760);      // 160 KB
    float* wsl   = (float*)((char*)d_out + 10649600);      // 160 KB
    float* vpart = (float*)((char*)d_out + 10813440);      // 256 KB
    float* M     = (float*)((char*)d_out + 11075584);      // 256 KB
    int*   idxg  = (int*)((char*)d_out + 11337728);        // 320 KB (ends 11.67 MB)
    // d_ws (read by k_out): ~352 KB total
    int*      top   = (int*)d_ws;                          // 6.4 KB (pad to 8K)
    float*    stage = (float*)((char*)d_ws + 8192);        // 320 KB
    float*    vm    = (float*)((char*)d_ws + 335872);      // 8 KB
    uint32_t* gmask = (uint32_t*)((char*)d_ws + 344064);   // 8 KB

    hipLaunchKernelGGL(k_index, dim3(320), dim3(256), 0, stream, idxg);
    hipLaunchKernelGGL(k_M, dim3(2048), dim3(256), 0, stream, Q, K, idxg, M);
    hipLaunchKernelGGL(k_topk, dim3(Bc * Hc), dim3(256), 0, stream, M, top, gmask);
    hipLaunchKernelGGL(k_attn_part, dim3(4096), dim3(64), 0, stream, Q, K, V, top,
                       wsO, wsm, wsl, vpart);
    hipLaunchKernelGGL(k_attn_comb, dim3(Bc * Hc * 8), dim3(256), 0, stream, wsO, wsm, wsl,
                       vpart, stage, vm);
    hipLaunchKernelGGL(k_out, dim3(4096), dim3(256), 0, stream, stage, vm, top, gmask, out);
}

// Round 11
// 96.323 us; speedup vs baseline: 1.3364x; 1.3364x over previous
//
#include <hip/hip_runtime.h>
#include <stdint.h>

// ProbSparse attention (Informer): B=4, L=2048, H=8, D=64, factor=5 -> U_part=u=40.
// out = broadcast mean(V) except top-40 rows per (b,h) get softmax(Q K^T/8) V.
// Row selection is bit-exact jax.random.randint(key(42),(2048,40),0,2048)
// under jax_threefry_partitionable=True (verified passing).
//
// R10 post-mortem: k_M is L2-BW-bound at minimal traffic (671 MB; warm-replay
// invariant) -> structural floor ~42 us. k_topk was the hidden 42 us: 40 serial
// argmax iters at 1.2% occupancy. R11: radix-select top-40 (4x8-bit passes,
// ~14 barriers vs ~120, set-equivalent to stable top-k; order is free since
// downstream is u-slot-consistent).

static constexpr int Bc = 4, Lc = 2048, Hc = 8, Dc = 64, NUc = 40;
static constexpr int NCH = 32, CHK = 64;  // key chunks for attention
static constexpr int UT = 10;             // queries per attn_part block (4 tiles)

struct TF2 { uint32_t a, b; };

__host__ __device__ constexpr uint32_t rotl32c(uint32_t x, int r) {
    return (x << r) | (x >> (32 - r));
}

// Threefry-2x32, 20 rounds (jax._src.prng.threefry2x32), constexpr-foldable.
__host__ __device__ constexpr TF2 tf2x32c(uint32_t k0, uint32_t k1, uint32_t x0, uint32_t x1) {
    uint32_t ks[3] = {k0, k1, k0 ^ k1 ^ 0x1BD11BDAu};
    const int R0[4] = {13, 15, 26, 6};
    const int R1[4] = {17, 29, 16, 24};
    x0 += ks[0];
    x1 += ks[1];
    for (int i = 0; i < 5; ++i) {
        const int* R = (i & 1) ? R1 : R0;
        for (int j = 0; j < 4; ++j) {
            x0 += x1;
            x1 = rotl32c(x1, R[j]);
            x1 ^= x0;
        }
        x0 += ks[(i + 1) % 3];
        x1 += ks[(i + 2) % 3] + (uint32_t)(i + 1);
    }
    return TF2{x0, x1};
}

// ---------------- k_index: sample indices, computed once ------------------------
__global__ __launch_bounds__(256) void k_index(int* __restrict__ idx) {
    constexpr TF2 K2 = tf2x32c(0u, 42u, 0u, 1u);  // second key of split(key(42))
    int j = blockIdx.x * 256 + threadIdx.x;       // < 81920
    TF2 r = tf2x32c(K2.a, K2.b, 0u, (uint32_t)j);
    idx[j] = (int)((r.a ^ r.b) & 2047u);
}

// ---------------- k_M: sampled sparsity measure, all 8 heads per wave -----------
// Wave per (b,q). Lane l holds flat floats [8l..8l+7] of the 512-float row
// (h = l>>3): K[b,kk,:,:] is contiguous 2KB -> both loads fully coalesced.
// L2-BW-bound at minimal traffic (671 MB) -- structural floor ~42 us (R10 PMC).
__global__ __launch_bounds__(256, 4) void k_M(const float* __restrict__ Q,
                                              const float* __restrict__ K,
                                              const int* __restrict__ idxg,
                                              float* __restrict__ M) {
    int lane = threadIdx.x & 63;
    int w = threadIdx.x >> 6;
    int blk = blockIdx.x;           // 2048 blocks
    int xcd = blk & 7;              // XCD owns half the q's of one b
    int local = blk >> 3;           // 0..255
    int b = xcd >> 1;
    int q = (xcd & 1) * 1024 + local * 4 + w;
    int h = lane >> 3;
    int myidx = (lane < 40) ? idxg[q * 40 + lane] : 0;

    const float4* Q4 = reinterpret_cast<const float4*>(Q);
    const float4* K4 = reinterpret_cast<const float4*>(K);
    size_t qb = (size_t)(b * Lc + q) * 128;  // float4 slots per (b,l) row
    float4 qv0 = Q4[qb + 2 * lane];
    float4 qv1 = Q4[qb + 2 * lane + 1];

    float mx8[8], sm8[8];
#pragma unroll
    for (int j = 0; j < 8; ++j) { mx8[j] = -INFINITY; sm8[j] = 0.f; }
#pragma unroll
    for (int i = 0; i < 5; ++i) {
#pragma unroll
        for (int j = 0; j < 8; ++j) {
            int kk = __shfl(myidx, i * 8 + j, 64);
            size_t rb = (size_t)(b * Lc + kk) * 128;
            float4 kv0 = K4[rb + 2 * lane];
            float4 kv1 = K4[rb + 2 * lane + 1];
            float pv = qv0.x * kv0.x + qv0.y * kv0.y + qv0.z * kv0.z + qv0.w * kv0.w +
                       qv1.x * kv1.x + qv1.y * kv1.y + qv1.z * kv1.z + qv1.w * kv1.w;
#pragma unroll
            for (int m = 1; m < 8; m <<= 1) pv += __shfl_xor(pv, m, 64);
            mx8[j] = fmaxf(mx8[j], pv);
            sm8[j] += pv;
        }
    }
    float mx = mx8[0], sm = sm8[0];
#pragma unroll
    for (int j = 1; j < 8; ++j) { mx = fmaxf(mx, mx8[j]); sm += sm8[j]; }
    if ((lane & 7) == 0) M[(b * 8 + h) * Lc + q] = mx - sm * (1.0f / 2048.0f);
}

// ---------------- k_topk: radix-select top-40 (set-equivalent to stable top_k) ---
// 4 passes of 8-bit digits over order-preserving uint keys; ties at the threshold
// resolved by smallest index. Output order arbitrary (downstream u-slot-consistent).
__global__ __launch_bounds__(256) void k_topk(const float* __restrict__ M, int* __restrict__ top,
                                              uint32_t* __restrict__ gmask) {
    __shared__ uint32_t hist[256];
    __shared__ uint32_t sh_bin, sh_need;
    __shared__ int sel[NUc];
    __shared__ int tie[128];
    __shared__ uint32_t selCnt, tieCnt;
    int bh = blockIdx.x;
    int t = threadIdx.x;
    uint32_t uk[8];
#pragma unroll
    for (int i = 0; i < 8; ++i) {
        uint32_t s = __float_as_uint(M[bh * Lc + i * 256 + t]);
        uk[i] = (s & 0x80000000u) ? ~s : (s | 0x80000000u);  // monotonic key
    }
    uint32_t prefix = 0, need = NUc;
    for (int pass = 0; pass < 4; ++pass) {
        int shift = 24 - 8 * pass;
        hist[t] = 0;
        __syncthreads();
#pragma unroll
        for (int i = 0; i < 8; ++i) {
            bool ok = (pass == 0) || ((uk[i] >> (shift + 8)) == prefix);
            if (ok) atomicAdd(&hist[(uk[i] >> shift) & 255u], 1u);
        }
        __syncthreads();
        if (t < 64) {  // single-wave suffix scan: lane l covers bins 4l..4l+3
            uint32_t c0 = hist[4 * t], c1 = hist[4 * t + 1];
            uint32_t c2 = hist[4 * t + 2], c3 = hist[4 * t + 3];
            uint32_t s = c0 + c1 + c2 + c3;
            uint32_t suf = s;  // will be sum over lanes t..63 (bins 4t..255)
#pragma unroll
            for (int m = 1; m < 64; m <<= 1) {
                uint32_t o = __shfl_down(suf, m, 64);
                if (t + m < 64) suf += o;
            }
            uint32_t above = suf - s;  // count in bins > 4t+3
            if (suf >= need && above < need) {  // crossing lane
                uint32_t rem = need - above;
                uint32_t bsel, cnt;
                if (c3 >= rem) { bsel = 4 * t + 3; cnt = rem; }
                else if (c3 + c2 >= rem) { bsel = 4 * t + 2; cnt = rem - c3; }
                else if (c3 + c2 + c1 >= rem) { bsel = 4 * t + 1; cnt = rem - c3 - c2; }
                else { bsel = 4 * t; cnt = rem - c3 - c2 - c1; }
                sh_bin = bsel;
                sh_need = cnt;
            }
        }
        __syncthreads();
        prefix = (pass == 0) ? sh_bin : ((prefix << 8) | sh_bin);
        need = sh_need;
        __syncthreads();
    }
    const uint32_t T = prefix;  // exact 32-bit key of the cutoff element
    if (t == 0) { selCnt = 0; tieCnt = 0; }
    __syncthreads();
#pragma unroll
    for (int i = 0; i < 8; ++i) {
        int idx = i * 256 + t;
        if (uk[i] > T) {
            uint32_t slot = atomicAdd(&selCnt, 1u);
            if (slot < NUc) sel[slot] = idx;
        } else if (uk[i] == T) {
            uint32_t slot = atomicAdd(&tieCnt, 1u);
            if (slot < 128) tie[slot] = idx;
        }
    }
    __syncthreads();
    if (t == 0) {  // take `need` smallest tie indices (stable top-k semantics)
        int n = (int)tieCnt;
        if (n > 128) n = 128;
        for (int a = 1; a < n; ++a) {  // insertion sort (n is tiny)
            int key = tie[a], c = a - 1;
            while (c >= 0 && tie[c] > key) { tie[c + 1] = tie[c]; --c; }
            tie[c + 1] = key;
        }
        uint32_t base = selCnt;
        for (uint32_t j = 0; j < need && base + j < NUc; ++j) sel[base + j] = tie[j];
    }
    __syncthreads();
    if (t < NUc) top[bh * NUc + t] = sel[t];
    if (t < 64) {
        uint32_t word = 0;
#pragma unroll
        for (int j = 0; j < NUc; ++j) {
            int s = sel[j];
            if ((s >> 5) == t) word |= 1u << (s & 31);
        }
        gmask[bh * 64 + t] = word;
    }
}

// ---------------- attention partials: 1-wave block = (bh, chunk, u-tile) ---------
// 4096 blocks of 64 threads (16 waves/CU). Shuffle-reduce softmax stats.
__global__ __launch_bounds__(64, 4) void k_attn_part(const float* __restrict__ Q,
                                                     const float* __restrict__ K,
                                                     const float* __restrict__ V,
                                                     const int* __restrict__ top,
                                                     float* __restrict__ wsO,
                                                     float* __restrict__ wsm,
                                                     float* __restrict__ wsl,
                                                     float* __restrict__ vpart) {
    __shared__ float Qs[UT][64];   // 2.5 KB
    __shared__ float pT[64][12];   // 3 KB (key-local, u + pad to float4 rows)
    __shared__ int tqs[UT];
    int blk = blockIdx.x;          // xcd-affine: 8 XCD x 4 bh x 32 chunk x 4 ut
    int xcd = blk & 7, local = blk >> 3;
    int bh = xcd * 4 + (local >> 7);
    int rem = local & 127;
    int chunk = rem >> 2, ut = rem & 3;
    int b = bh >> 3, h = bh & 7;
    int t = threadIdx.x;  // 0..63 (= lane = key-slot = dim)

    if (t < UT) tqs[t] = top[bh * NUc + ut * UT + t];
    __syncthreads();
#pragma unroll
    for (int j = 0; j < UT; ++j)
        Qs[j][t] = Q[(((size_t)(b * Lc + tqs[j])) * Hc + h) * Dc + t];
    __syncthreads();

    // scores: thread t owns key kg = chunk*64 + t; acc[u] = dot(Q[u], K[kg]) / 8
    int kg = chunk * CHK + t;
    const float4* Kr = reinterpret_cast<const float4*>(&K[(((size_t)(b * Lc + kg)) * Hc + h) * Dc]);
    float acc[UT];
#pragma unroll
    for (int u = 0; u < UT; ++u) acc[u] = 0.f;
#pragma unroll
    for (int i = 0; i < 16; ++i) {
        float4 kv = Kr[i];
#pragma unroll
        for (int u = 0; u < UT; ++u) {
            float4 qv = *reinterpret_cast<const float4*>(&Qs[u][i * 4]);
            acc[u] += qv.x * kv.x + qv.y * kv.y + qv.z * kv.z + qv.w * kv.w;
        }
    }
#pragma unroll
    for (int u = 0; u < UT; ++u) acc[u] *= 0.125f;
    // per-u max over the 64 keys via wave butterfly
    float mr[UT];
#pragma unroll
    for (int u = 0; u < UT; ++u) {
        float v = acc[u];
#pragma unroll
        for (int m = 1; m < 64; m <<= 1) v = fmaxf(v, __shfl_xor(v, m, 64));
        mr[u] = v;
    }
    // exp + stage transposed P into LDS
    float pr[UT];
#pragma unroll
    for (int u = 0; u < UT; ++u) {
        pr[u] = __expf(acc[u] - mr[u]);
        pT[t][u] = pr[u];
    }
    // per-u sum via wave butterfly
    float sr[UT];
#pragma unroll
    for (int u = 0; u < UT; ++u) {
        float v = pr[u];
#pragma unroll
        for (int m = 1; m < 64; m <<= 1) v += __shfl_xor(v, m, 64);
        sr[u] = v;
    }
    // write chunk stats (values wave-uniform; lane u writes entry u)
    int sbase = (bh * NCH + chunk) * NUc + ut * UT;
#pragma unroll
    for (int u = 0; u < UT; ++u) {
        if (t == u) {
            wsm[sbase + u] = mr[u];
            wsl[sbase + u] = sr[u];
        }
    }
    __syncthreads();
    // PV over the 64 keys: lane = d, acc[u] = sum_k p[u][k] * V[k][d].
    // Free byproduct (ut==0 only): vs = sum_k V[k][d] for the V-mean output.
#pragma unroll
    for (int u = 0; u < UT; ++u) acc[u] = 0.f;
    float vs = 0.f;
    const float* Vbh = V + ((size_t)b * Lc * Hc + h) * Dc;
    for (int k = 0; k < 64; ++k) {
        float vv = Vbh[(size_t)(chunk * CHK + k) * 512 + t];
        vs += vv;
        float4 pa = *reinterpret_cast<const float4*>(&pT[k][0]);
        float4 pb = *reinterpret_cast<const float4*>(&pT[k][4]);
        float2 pc = *reinterpret_cast<const float2*>(&pT[k][8]);
        acc[0] += pa.x * vv; acc[1] += pa.y * vv; acc[2] += pa.z * vv; acc[3] += pa.w * vv;
        acc[4] += pb.x * vv; acc[5] += pb.y * vv; acc[6] += pb.z * vv; acc[7] += pb.w * vv;
        acc[8] += pc.x * vv; acc[9] += pc.y * vv;
    }
    if (ut == 0) vpart[(bh * NCH + chunk) * 64 + t] = vs;
    size_t obase = (size_t)(bh * NCH + chunk) * 2560 + (size_t)(ut * UT) * 64;
#pragma unroll
    for (int u = 0; u < UT; ++u) wsO[obase + u * 64 + t] = acc[u];
}

// ---------------- combine 32 chunk-partials -> staged rows + finish V-mean -------
// grid = 32 bh x 8 u-tiles (5 u each) = 256 blocks.
__global__ __launch_bounds__(256) void k_attn_comb(const float* __restrict__ wsO,
                                                   const float* __restrict__ wsm,
                                                   const float* __restrict__ wsl,
                                                   const float* __restrict__ vpart,
                                                   float* __restrict__ stage,
                                                   float* __restrict__ vm) {
    __shared__ float cm[NCH][5], cl[NCH][5], cf[NCH][5];
    int blk = blockIdx.x;  // bh*8 + ut
    int ut = blk & 7, bh = blk >> 3;
    int t = threadIdx.x;
    for (int i = t; i < NCH * 5; i += 256) {
        int c = i / 5, j = i % 5;
        cm[c][j] = wsm[(bh * NCH + c) * NUc + ut * 5 + j];
        cl[c][j] = wsl[(bh * NCH + c) * NUc + ut * 5 + j];
    }
    __syncthreads();
    if (t < 5) {
        float m = -INFINITY;
#pragma unroll
        for (int c = 0; c < NCH; ++c) m = fmaxf(m, cm[c][t]);
        float L = 0.f;
#pragma unroll
        for (int c = 0; c < NCH; ++c) {
            float f = __expf(cm[c][t] - m);
            L += cl[c][t] * f;
            cf[c][t] = f;
        }
        float inv = 1.0f / L;
#pragma unroll
        for (int c = 0; c < NCH; ++c) cf[c][t] *= inv;
    }
    if (ut == 0 && t >= 64 && t < 128) {  // finish V-mean once per bh
        int d = t - 64;
        float s = 0.f;
#pragma unroll
        for (int c = 0; c < NCH; ++c) s += vpart[(bh * NCH + c) * 64 + d];
        vm[bh * 64 + d] = s * (1.0f / 2048.0f);
    }
    __syncthreads();
    for (int i = t; i < 5 * 64; i += 256) {
        int j = i >> 6, d = i & 63;
        float val = 0.f;
#pragma unroll
        for (int c = 0; c < NCH; ++c)
            val += wsO[((size_t)(bh * NCH + c)) * 2560 + (ut * 5 + j) * 64 + d] * cf[c][j];
        stage[(size_t)bh * 2560 + (ut * 5 + j) * 64 + d] = val;
    }
}

// ---------------- fused output: vmean fill + attended-row scatter ----------------
__global__ void k_out(const float* __restrict__ stage, const float* __restrict__ vm,
                      const int* __restrict__ top, const uint32_t* __restrict__ gmask,
                      float* __restrict__ out) {
    int o4 = blockIdx.x * blockDim.x + threadIdx.x;  // over 1M float4
    if (o4 >= Bc * Lc * Hc * (Dc / 4)) return;
    int dq = o4 & 15;
    int h = (o4 >> 4) & 7;
    int bl = o4 >> 7;  // b*2048 + l
    int b = bl >> 11, l = bl & 2047;
    int bh = b * 8 + h;
    float4 v;
    uint32_t wmask = gmask[bh * 64 + (l >> 5)];
    if ((wmask >> (l & 31)) & 1u) {
        int u = 0;
#pragma unroll
        for (int j = 0; j < NUc; ++j)
            if (top[bh * NUc + j] == l) u = j;
        v = reinterpret_cast<const float4*>(stage)[(bh * NUc + u) * 16 + dq];
    } else {
        v = reinterpret_cast<const float4*>(vm)[bh * 16 + dq];
    }
    reinterpret_cast<float4*>(out)[o4] = v;
}

extern "C" void kernel_launch(void* const* d_in, const int* in_sizes, int n_in,
                              void* d_out, int out_size, void* d_ws, size_t ws_size,
                              hipStream_t stream) {
    (void)in_sizes; (void)n_in; (void)out_size; (void)ws_size;
    const float* Q = (const float*)d_in[0];
    const float* K = (const float*)d_in[1];
    const float* V = (const float*)d_in[2];
    float* out = (float*)d_out;

    // d_out-as-scratch (16.78 MB; all consumed before k_out overwrites it):
    float* wsO   = (float*)d_out;                          // 0 .. 10.49 MB
    float* wsm   = (float*)((char*)d_out + 10485760);      // 160 KB
    float* wsl   = (float*)((char*)d_out + 10649600);      // 160 KB
    float* vpart = (float*)((char*)d_out + 10813440);      // 256 KB
    float* M     = (float*)((char*)d_out + 11075584);      // 256 KB
    int*   idxg  = (int*)((char*)d_out + 11337728);        // 320 KB (ends 11.67 MB)
    // d_ws (read by k_out): ~352 KB total
    int*      top   = (int*)d_ws;                          // 6.4 KB (pad to 8K)
    float*    stage = (float*)((char*)d_ws + 8192);        // 320 KB
    float*    vm    = (float*)((char*)d_ws + 335872);      // 8 KB
    uint32_t* gmask = (uint32_t*)((char*)d_ws + 344064);   // 8 KB

    hipLaunchKernelGGL(k_index, dim3(320), dim3(256), 0, stream, idxg);
    hipLaunchKernelGGL(k_M, dim3(2048), dim3(256), 0, stream, Q, K, idxg, M);
    hipLaunchKernelGGL(k_topk, dim3(Bc * Hc), dim3(256), 0, stream, M, top, gmask);
    hipLaunchKernelGGL(k_attn_part, dim3(4096), dim3(64), 0, stream, Q, K, V, top,
                       wsO, wsm, wsl, vpart);
    hipLaunchKernelGGL(k_attn_comb, dim3(Bc * Hc * 8), dim3(256), 0, stream, wsO, wsm, wsl,
                       vpart, stage, vm);
    hipLaunchKernelGGL(k_out, dim3(4096), dim3(256), 0, stream, stage, vm, top, gmask, out);
}

// Round 12
// 91.959 us; speedup vs baseline: 1.3998x; 1.0475x over previous
//
#include <hip/hip_runtime.h>
#include <stdint.h>

// ProbSparse attention (Informer): B=4, L=2048, H=8, D=64, factor=5 -> U_part=u=40.
// out = broadcast mean(V) except top-40 rows per (b,h) get softmax(Q K^T/8) V.
// Row selection is bit-exact jax.random.randint(key(42),(2048,40),0,2048)
// under jax_threefry_partitionable=True (verified passing).
//
// R11 post-mortem: radix topk worked (42us gone). k_M = structural floor
// (L2->CU path at minimal 671MB traffic; warm-replay invariant). ~16us left in
// launch gaps + staging stages. R12: de-stage the pipeline: fuse index into k_M,
// V-mean via atomicAdd from attn_part's V stream, and (ws_size permitting) move
// wsO/wsm/wsl to d_ws so k_out inlines the chunk combine -> 4 kernels.

static constexpr int Bc = 4, Lc = 2048, Hc = 8, Dc = 64, NUc = 40;
static constexpr int NCH = 32, CHK = 64;  // key chunks for attention
static constexpr int UT = 10;             // queries per attn_part wave-unit (4 tiles)

struct TF2 { uint32_t a, b; };

__host__ __device__ constexpr uint32_t rotl32c(uint32_t x, int r) {
    return (x << r) | (x >> (32 - r));
}

// Threefry-2x32, 20 rounds (jax._src.prng.threefry2x32), constexpr-foldable.
__host__ __device__ constexpr TF2 tf2x32c(uint32_t k0, uint32_t k1, uint32_t x0, uint32_t x1) {
    uint32_t ks[3] = {k0, k1, k0 ^ k1 ^ 0x1BD11BDAu};
    const int R0[4] = {13, 15, 26, 6};
    const int R1[4] = {17, 29, 16, 24};
    x0 += ks[0];
    x1 += ks[1];
    for (int i = 0; i < 5; ++i) {
        const int* R = (i & 1) ? R1 : R0;
        for (int j = 0; j < 4; ++j) {
            x0 += x1;
            x1 = rotl32c(x1, R[j]);
            x1 ^= x0;
        }
        x0 += ks[(i + 1) % 3];
        x1 += ks[(i + 2) % 3] + (uint32_t)(i + 1);
    }
    return TF2{x0, x1};
}

// ---------------- k_M: sampled sparsity measure, all 8 heads per wave -----------
// Wave per (b,q); lane l holds flat floats [8l..8l+7] of the contiguous 2KB row.
// Sample indices computed inline (Threefry, lane s<40, j=q*40+s). Blocks 0..7
// also zero vm (accumulated later by attn_part atomics).
__global__ __launch_bounds__(256, 4) void k_M(const float* __restrict__ Q,
                                              const float* __restrict__ K,
                                              float* __restrict__ M,
                                              float* __restrict__ vm) {
    constexpr TF2 K2 = tf2x32c(0u, 42u, 0u, 1u);  // second key of split(key(42))
    int lane = threadIdx.x & 63;
    int w = threadIdx.x >> 6;
    int blk = blockIdx.x;           // 2048 blocks
    if (blk < 8) vm[blk * 256 + threadIdx.x] = 0.f;
    int xcd = blk & 7;              // XCD owns half the q's of one b
    int local = blk >> 3;           // 0..255
    int b = xcd >> 1;
    int q = (xcd & 1) * 1024 + local * 4 + w;
    int h = lane >> 3;
    int myidx = 0;
    if (lane < 40) {
        TF2 r = tf2x32c(K2.a, K2.b, 0u, (uint32_t)(q * 40 + lane));
        myidx = (int)((r.a ^ r.b) & 2047u);
    }

    const float4* Q4 = reinterpret_cast<const float4*>(Q);
    const float4* K4 = reinterpret_cast<const float4*>(K);
    size_t qb = (size_t)(b * Lc + q) * 128;  // float4 slots per (b,l) row
    float4 qv0 = Q4[qb + 2 * lane];
    float4 qv1 = Q4[qb + 2 * lane + 1];

    float mx8[8], sm8[8];
#pragma unroll
    for (int j = 0; j < 8; ++j) { mx8[j] = -INFINITY; sm8[j] = 0.f; }
#pragma unroll
    for (int i = 0; i < 5; ++i) {
#pragma unroll
        for (int j = 0; j < 8; ++j) {
            int kk = __shfl(myidx, i * 8 + j, 64);
            size_t rb = (size_t)(b * Lc + kk) * 128;
            float4 kv0 = K4[rb + 2 * lane];
            float4 kv1 = K4[rb + 2 * lane + 1];
            float pv = qv0.x * kv0.x + qv0.y * kv0.y + qv0.z * kv0.z + qv0.w * kv0.w +
                       qv1.x * kv1.x + qv1.y * kv1.y + qv1.z * kv1.z + qv1.w * kv1.w;
#pragma unroll
            for (int m = 1; m < 8; m <<= 1) pv += __shfl_xor(pv, m, 64);
            mx8[j] = fmaxf(mx8[j], pv);
            sm8[j] += pv;
        }
    }
    float mx = mx8[0], sm = sm8[0];
#pragma unroll
    for (int j = 1; j < 8; ++j) { mx = fmaxf(mx, mx8[j]); sm += sm8[j]; }
    if ((lane & 7) == 0) M[(b * 8 + h) * Lc + q] = mx - sm * (1.0f / 2048.0f);
}

// ---------------- k_topk: radix-select top-40 (set-equivalent to stable top_k) ---
__global__ __launch_bounds__(256) void k_topk(const float* __restrict__ M, int* __restrict__ top,
                                              uint32_t* __restrict__ gmask) {
    __shared__ uint32_t hist[256];
    __shared__ uint32_t sh_bin, sh_need;
    __shared__ int sel[NUc];
    __shared__ int tie[128];
    __shared__ uint32_t selCnt, tieCnt;
    int bh = blockIdx.x;
    int t = threadIdx.x;
    uint32_t uk[8];
#pragma unroll
    for (int i = 0; i < 8; ++i) {
        uint32_t s = __float_as_uint(M[bh * Lc + i * 256 + t]);
        uk[i] = (s & 0x80000000u) ? ~s : (s | 0x80000000u);  // monotonic key
    }
    uint32_t prefix = 0, need = NUc;
    for (int pass = 0; pass < 4; ++pass) {
        int shift = 24 - 8 * pass;
        hist[t] = 0;
        __syncthreads();
#pragma unroll
        for (int i = 0; i < 8; ++i) {
            bool ok = (pass == 0) || ((uk[i] >> (shift + 8)) == prefix);
            if (ok) atomicAdd(&hist[(uk[i] >> shift) & 255u], 1u);
        }
        __syncthreads();
        if (t < 64) {  // single-wave suffix scan: lane l covers bins 4l..4l+3
            uint32_t c0 = hist[4 * t], c1 = hist[4 * t + 1];
            uint32_t c2 = hist[4 * t + 2], c3 = hist[4 * t + 3];
            uint32_t s = c0 + c1 + c2 + c3;
            uint32_t suf = s;
#pragma unroll
            for (int m = 1; m < 64; m <<= 1) {
                uint32_t o = __shfl_down(suf, m, 64);
                if (t + m < 64) suf += o;
            }
            uint32_t above = suf - s;
            if (suf >= need && above < need) {  // crossing lane
                uint32_t rem = need - above;
                uint32_t bsel, cnt;
                if (c3 >= rem) { bsel = 4 * t + 3; cnt = rem; }
                else if (c3 + c2 >= rem) { bsel = 4 * t + 2; cnt = rem - c3; }
                else if (c3 + c2 + c1 >= rem) { bsel = 4 * t + 1; cnt = rem - c3 - c2; }
                else { bsel = 4 * t; cnt = rem - c3 - c2 - c1; }
                sh_bin = bsel;
                sh_need = cnt;
            }
        }
        __syncthreads();
        prefix = (pass == 0) ? sh_bin : ((prefix << 8) | sh_bin);
        need = sh_need;
        __syncthreads();
    }
    const uint32_t T = prefix;
    if (t == 0) { selCnt = 0; tieCnt = 0; }
    __syncthreads();
#pragma unroll
    for (int i = 0; i < 8; ++i) {
        int idx = i * 256 + t;
        if (uk[i] > T) {
            uint32_t slot = atomicAdd(&selCnt, 1u);
            if (slot < NUc) sel[slot] = idx;
        } else if (uk[i] == T) {
            uint32_t slot = atomicAdd(&tieCnt, 1u);
            if (slot < 128) tie[slot] = idx;
        }
    }
    __syncthreads();
    if (t == 0) {  // take `need` smallest tie indices (stable top-k semantics)
        int n = (int)tieCnt;
        if (n > 128) n = 128;
        for (int a = 1; a < n; ++a) {
            int key = tie[a], c = a - 1;
            while (c >= 0 && tie[c] > key) { tie[c + 1] = tie[c]; --c; }
            tie[c + 1] = key;
        }
        uint32_t base = selCnt;
        for (uint32_t j = 0; j < need && base + j < NUc; ++j) sel[base + j] = tie[j];
    }
    __syncthreads();
    if (t < NUc) top[bh * NUc + t] = sel[t];
    if (t < 64) {
        uint32_t word = 0;
#pragma unroll
        for (int j = 0; j < NUc; ++j) {
            int s = sel[j];
            if ((s >> 5) == t) word |= 1u << (s & 31);
        }
        gmask[bh * 64 + t] = word;
    }
}

// ---------------- attention partials: 1-wave block = (bh, chunk, u-tile) ---------
// 4096 blocks of 64 threads. V-mean accumulated into vm via atomicAdd (ut==0).
__global__ __launch_bounds__(64, 4) void k_attn_part(const float* __restrict__ Q,
                                                     const float* __restrict__ K,
                                                     const float* __restrict__ V,
                                                     const int* __restrict__ top,
                                                     float* __restrict__ wsO,
                                                     float* __restrict__ wsm,
                                                     float* __restrict__ wsl,
                                                     float* __restrict__ vm) {
    __shared__ float Qs[UT][64];
    __shared__ float pT[64][12];
    __shared__ int tqs[UT];
    int blk = blockIdx.x;          // xcd-affine: 8 XCD x 4 bh x 32 chunk x 4 ut
    int xcd = blk & 7, local = blk >> 3;
    int bh = xcd * 4 + (local >> 7);
    int rem = local & 127;
    int chunk = rem >> 2, ut = rem & 3;
    int b = bh >> 3, h = bh & 7;
    int t = threadIdx.x;  // 0..63 (= lane = key-slot = dim)

    if (t < UT) tqs[t] = top[bh * NUc + ut * UT + t];
    __syncthreads();
#pragma unroll
    for (int j = 0; j < UT; ++j)
        Qs[j][t] = Q[(((size_t)(b * Lc + tqs[j])) * Hc + h) * Dc + t];
    __syncthreads();

    int kg = chunk * CHK + t;
    const float4* Kr = reinterpret_cast<const float4*>(&K[(((size_t)(b * Lc + kg)) * Hc + h) * Dc]);
    float acc[UT];
#pragma unroll
    for (int u = 0; u < UT; ++u) acc[u] = 0.f;
#pragma unroll
    for (int i = 0; i < 16; ++i) {
        float4 kv = Kr[i];
#pragma unroll
        for (int u = 0; u < UT; ++u) {
            float4 qv = *reinterpret_cast<const float4*>(&Qs[u][i * 4]);
            acc[u] += qv.x * kv.x + qv.y * kv.y + qv.z * kv.z + qv.w * kv.w;
        }
    }
#pragma unroll
    for (int u = 0; u < UT; ++u) acc[u] *= 0.125f;
    float mr[UT];
#pragma unroll
    for (int u = 0; u < UT; ++u) {
        float v = acc[u];
#pragma unroll
        for (int m = 1; m < 64; m <<= 1) v = fmaxf(v, __shfl_xor(v, m, 64));
        mr[u] = v;
    }
    float pr[UT];
#pragma unroll
    for (int u = 0; u < UT; ++u) {
        pr[u] = __expf(acc[u] - mr[u]);
        pT[t][u] = pr[u];
    }
    float sr[UT];
#pragma unroll
    for (int u = 0; u < UT; ++u) {
        float v = pr[u];
#pragma unroll
        for (int m = 1; m < 64; m <<= 1) v += __shfl_xor(v, m, 64);
        sr[u] = v;
    }
    int sbase = (bh * NCH + chunk) * NUc + ut * UT;
#pragma unroll
    for (int u = 0; u < UT; ++u) {
        if (t == u) {
            wsm[sbase + u] = mr[u];
            wsl[sbase + u] = sr[u];
        }
    }
    __syncthreads();
#pragma unroll
    for (int u = 0; u < UT; ++u) acc[u] = 0.f;
    float vs = 0.f;
    const float* Vbh = V + ((size_t)b * Lc * Hc + h) * Dc;
    for (int k = 0; k < 64; ++k) {
        float vv = Vbh[(size_t)(chunk * CHK + k) * 512 + t];
        vs += vv;
        float4 pa = *reinterpret_cast<const float4*>(&pT[k][0]);
        float4 pb = *reinterpret_cast<const float4*>(&pT[k][4]);
        float2 pc = *reinterpret_cast<const float2*>(&pT[k][8]);
        acc[0] += pa.x * vv; acc[1] += pa.y * vv; acc[2] += pa.z * vv; acc[3] += pa.w * vv;
        acc[4] += pb.x * vv; acc[5] += pb.y * vv; acc[6] += pb.z * vv; acc[7] += pb.w * vv;
        acc[8] += pc.x * vv; acc[9] += pc.y * vv;
    }
    if (ut == 0) atomicAdd(&vm[bh * 64 + t], vs * (1.0f / 2048.0f));
    size_t obase = (size_t)(bh * NCH + chunk) * 2560 + (size_t)(ut * UT) * 64;
#pragma unroll
    for (int u = 0; u < UT; ++u) wsO[obase + u * 64 + t] = acc[u];
}

// ---------------- Path A: fused output with inline 32-chunk combine --------------
// Safe because wsO/wsm/wsl live in d_ws (no overlap with the out buffer).
__global__ void k_out_inl(const float* __restrict__ wsO, const float* __restrict__ wsm,
                          const float* __restrict__ wsl, const float* __restrict__ vm,
                          const int* __restrict__ top, const uint32_t* __restrict__ gmask,
                          float* __restrict__ out) {
    int o4 = blockIdx.x * blockDim.x + threadIdx.x;  // over 1M float4
    if (o4 >= Bc * Lc * Hc * (Dc / 4)) return;
    int dq = o4 & 15;
    int h = (o4 >> 4) & 7;
    int bl = o4 >> 7;
    int b = bl >> 11, l = bl & 2047;
    int bh = b * 8 + h;
    float4 v;
    uint32_t wmask = gmask[bh * 64 + (l >> 5)];
    if ((wmask >> (l & 31)) & 1u) {
        int u = 0;
#pragma unroll
        for (int j = 0; j < NUc; ++j)
            if (top[bh * NUc + j] == l) u = j;
        float cf[NCH];
        float m = -INFINITY;
#pragma unroll
        for (int c = 0; c < NCH; ++c) {
            cf[c] = wsm[(bh * NCH + c) * NUc + u];
            m = fmaxf(m, cf[c]);
        }
        float L = 0.f;
#pragma unroll
        for (int c = 0; c < NCH; ++c) {
            float e = __expf(cf[c] - m);
            L += wsl[(bh * NCH + c) * NUc + u] * e;
            cf[c] = e;
        }
        const float4* W4 = reinterpret_cast<const float4*>(wsO);
        float4 a = make_float4(0.f, 0.f, 0.f, 0.f);
#pragma unroll
        for (int c = 0; c < NCH; ++c) {
            float4 o = W4[(size_t)(bh * NCH + c) * 640 + u * 16 + dq];
            a.x += o.x * cf[c]; a.y += o.y * cf[c]; a.z += o.z * cf[c]; a.w += o.w * cf[c];
        }
        float inv = 1.0f / L;
        v = make_float4(a.x * inv, a.y * inv, a.z * inv, a.w * inv);
    } else {
        v = reinterpret_cast<const float4*>(vm)[bh * 16 + dq];
    }
    reinterpret_cast<float4*>(out)[o4] = v;
}

// ---------------- Path B fallback: comb (stats only) + staged out ----------------
__global__ __launch_bounds__(256) void k_comb(const float* __restrict__ wsO,
                                              const float* __restrict__ wsm,
                                              const float* __restrict__ wsl,
                                              float* __restrict__ stage) {
    __shared__ float cm[NCH][5], cl[NCH][5], cf[NCH][5];
    int blk = blockIdx.x;  // bh*8 + ut
    int ut = blk & 7, bh = blk >> 3;
    int t = threadIdx.x;
    for (int i = t; i < NCH * 5; i += 256) {
        int c = i / 5, j = i % 5;
        cm[c][j] = wsm[(bh * NCH + c) * NUc + ut * 5 + j];
        cl[c][j] = wsl[(bh * NCH + c) * NUc + ut * 5 + j];
    }
    __syncthreads();
    if (t < 5) {
        float m = -INFINITY;
#pragma unroll
        for (int c = 0; c < NCH; ++c) m = fmaxf(m, cm[c][t]);
        float L = 0.f;
#pragma unroll
        for (int c = 0; c < NCH; ++c) {
            float f = __expf(cm[c][t] - m);
            L += cl[c][t] * f;
            cf[c][t] = f;
        }
        float inv = 1.0f / L;
#pragma unroll
        for (int c = 0; c < NCH; ++c) cf[c][t] *= inv;
    }
    __syncthreads();
    for (int i = t; i < 5 * 64; i += 256) {
        int j = i >> 6, d = i & 63;
        float val = 0.f;
#pragma unroll
        for (int c = 0; c < NCH; ++c)
            val += wsO[((size_t)(bh * NCH + c)) * 2560 + (ut * 5 + j) * 64 + d] * cf[c][j];
        stage[(size_t)bh * 2560 + (ut * 5 + j) * 64 + d] = val;
    }
}

__global__ void k_out(const float* __restrict__ stage, const float* __restrict__ vm,
                      const int* __restrict__ top, const uint32_t* __restrict__ gmask,
                      float* __restrict__ out) {
    int o4 = blockIdx.x * blockDim.x + threadIdx.x;
    if (o4 >= Bc * Lc * Hc * (Dc / 4)) return;
    int dq = o4 & 15;
    int h = (o4 >> 4) & 7;
    int bl = o4 >> 7;
    int b = bl >> 11, l = bl & 2047;
    int bh = b * 8 + h;
    float4 v;
    uint32_t wmask = gmask[bh * 64 + (l >> 5)];
    if ((wmask >> (l & 31)) & 1u) {
        int u = 0;
#pragma unroll
        for (int j = 0; j < NUc; ++j)
            if (top[bh * NUc + j] == l) u = j;
        v = reinterpret_cast<const float4*>(stage)[(bh * NUc + u) * 16 + dq];
    } else {
        v = reinterpret_cast<const float4*>(vm)[bh * 16 + dq];
    }
    reinterpret_cast<float4*>(out)[o4] = v;
}

extern "C" void kernel_launch(void* const* d_in, const int* in_sizes, int n_in,
                              void* d_out, int out_size, void* d_ws, size_t ws_size,
                              hipStream_t stream) {
    (void)in_sizes; (void)n_in; (void)out_size;
    const float* Q = (const float*)d_in[0];
    const float* K = (const float*)d_in[1];
    const float* V = (const float*)d_in[2];
    float* out = (float*)d_out;

    // Common small d_ws buffers:
    int*      top   = (int*)d_ws;                          // 6.4 KB (pad to 8K)
    float*    vm    = (float*)((char*)d_ws + 8192);        // 8 KB
    uint32_t* gmask = (uint32_t*)((char*)d_ws + 16384);    // 8 KB
    // M always lives high in d_out (consumed by k_topk before any out writes):
    float* M = (float*)((char*)d_out + 11075584);          // 256 KB

    const bool bigws = ws_size >= 11534336;  // deterministic per-harness

    if (bigws) {
        // Path A: partials in d_ws -> no comb kernel, k_out combines inline.
        float* wsm = (float*)((char*)d_ws + 32768);        // 160 KB
        float* wsl = (float*)((char*)d_ws + 196608);       // 160 KB
        float* wsO = (float*)((char*)d_ws + 393216);       // 10.49 MB (ends ~10.9 MB)
        hipLaunchKernelGGL(k_M, dim3(2048), dim3(256), 0, stream, Q, K, M, vm);
        hipLaunchKernelGGL(k_topk, dim3(Bc * Hc), dim3(256), 0, stream, M, top, gmask);
        hipLaunchKernelGGL(k_attn_part, dim3(4096), dim3(64), 0, stream, Q, K, V, top,
                           wsO, wsm, wsl, vm);
        hipLaunchKernelGGL(k_out_inl, dim3(4096), dim3(256), 0, stream, wsO, wsm, wsl, vm,
                           top, gmask, out);
    } else {
        // Path B: partials in d_out, staged combine (race-free vs out writes).
        float* wsO   = (float*)d_out;                      // 10.49 MB
        float* wsm   = (float*)((char*)d_out + 10485760);  // 160 KB
        float* wsl   = (float*)((char*)d_out + 10649600);  // 160 KB
        float* stage = (float*)((char*)d_ws + 24576);      // 320 KB
        hipLaunchKernelGGL(k_M, dim3(2048), dim3(256), 0, stream, Q, K, M, vm);
        hipLaunchKernelGGL(k_topk, dim3(Bc * Hc), dim3(256), 0, stream, M, top, gmask);
        hipLaunchKernelGGL(k_attn_part, dim3(4096), dim3(64), 0, stream, Q, K, V, top,
                           wsO, wsm, wsl, vm);
        hipLaunchKernelGGL(k_comb, dim3(Bc * Hc * 8), dim3(256), 0, stream, wsO, wsm, wsl,
                           stage);
        hipLaunchKernelGGL(k_out, dim3(4096), dim3(256), 0, stream, stage, vm, top, gmask,
                           out);
    }
}

// Round 13
// 90.722 us; speedup vs baseline: 1.4189x; 1.0136x over previous
//
#include <hip/hip_runtime.h>
#include <stdint.h>

// ProbSparse attention (Informer): B=4, L=2048, H=8, D=64, factor=5 -> U_part=u=40.
// out = broadcast mean(V) except top-40 rows per (b,h) get softmax(Q K^T/8) V.
// Row selection is bit-exact jax.random.randint(key(42),(2048,40),0,2048)
// under jax_threefry_partitionable=True (verified passing).
//
// R12 post-mortem: k_M = structural floor (671MB minimal L2->CU at ~62 B/cyc/CU).
// Hidden ~30us was attn_part: 64-segment K loads (thread-owns-row) + 4x ut-tile
// re-reads of K and V. R13: merge ut tiles into 256-thread blocks (1024 blocks),
// LDS-stage K with 4-segment staging pattern; V read once, coalesced.

static constexpr int Bc = 4, Lc = 2048, Hc = 8, Dc = 64, NUc = 40;
static constexpr int NCH = 32, CHK = 64;  // key chunks for attention
static constexpr int UT = 10;             // queries per wave (4 waves = 40 u)

struct TF2 { uint32_t a, b; };

__host__ __device__ constexpr uint32_t rotl32c(uint32_t x, int r) {
    return (x << r) | (x >> (32 - r));
}

// Threefry-2x32, 20 rounds (jax._src.prng.threefry2x32), constexpr-foldable.
__host__ __device__ constexpr TF2 tf2x32c(uint32_t k0, uint32_t k1, uint32_t x0, uint32_t x1) {
    uint32_t ks[3] = {k0, k1, k0 ^ k1 ^ 0x1BD11BDAu};
    const int R0[4] = {13, 15, 26, 6};
    const int R1[4] = {17, 29, 16, 24};
    x0 += ks[0];
    x1 += ks[1];
    for (int i = 0; i < 5; ++i) {
        const int* R = (i & 1) ? R1 : R0;
        for (int j = 0; j < 4; ++j) {
            x0 += x1;
            x1 = rotl32c(x1, R[j]);
            x1 ^= x0;
        }
        x0 += ks[(i + 1) % 3];
        x1 += ks[(i + 2) % 3] + (uint32_t)(i + 1);
    }
    return TF2{x0, x1};
}

// ---------------- k_M: sampled sparsity measure, all 8 heads per wave -----------
// Wave per (b,q); lane l holds flat floats [8l..8l+7] of the contiguous 2KB row.
// Structural floor: minimal 671MB L2->CU traffic at per-CU fetch ceiling (R10-R12).
__global__ __launch_bounds__(256, 4) void k_M(const float* __restrict__ Q,
                                              const float* __restrict__ K,
                                              float* __restrict__ M,
                                              float* __restrict__ vm) {
    constexpr TF2 K2 = tf2x32c(0u, 42u, 0u, 1u);  // second key of split(key(42))
    int lane = threadIdx.x & 63;
    int w = threadIdx.x >> 6;
    int blk = blockIdx.x;           // 2048 blocks
    if (blk < 8) vm[blk * 256 + threadIdx.x] = 0.f;
    int xcd = blk & 7;              // XCD owns half the q's of one b
    int local = blk >> 3;           // 0..255
    int b = xcd >> 1;
    int q = (xcd & 1) * 1024 + local * 4 + w;
    int h = lane >> 3;
    int myidx = 0;
    if (lane < 40) {
        TF2 r = tf2x32c(K2.a, K2.b, 0u, (uint32_t)(q * 40 + lane));
        myidx = (int)((r.a ^ r.b) & 2047u);
    }

    const float4* Q4 = reinterpret_cast<const float4*>(Q);
    const float4* K4 = reinterpret_cast<const float4*>(K);
    size_t qb = (size_t)(b * Lc + q) * 128;  // float4 slots per (b,l) row
    float4 qv0 = Q4[qb + 2 * lane];
    float4 qv1 = Q4[qb + 2 * lane + 1];

    float mx8[8], sm8[8];
#pragma unroll
    for (int j = 0; j < 8; ++j) { mx8[j] = -INFINITY; sm8[j] = 0.f; }
#pragma unroll
    for (int i = 0; i < 5; ++i) {
#pragma unroll
        for (int j = 0; j < 8; ++j) {
            int kk = __shfl(myidx, i * 8 + j, 64);
            size_t rb = (size_t)(b * Lc + kk) * 128;
            float4 kv0 = K4[rb + 2 * lane];
            float4 kv1 = K4[rb + 2 * lane + 1];
            float pv = qv0.x * kv0.x + qv0.y * kv0.y + qv0.z * kv0.z + qv0.w * kv0.w +
                       qv1.x * kv1.x + qv1.y * kv1.y + qv1.z * kv1.z + qv1.w * kv1.w;
#pragma unroll
            for (int m = 1; m < 8; m <<= 1) pv += __shfl_xor(pv, m, 64);
            mx8[j] = fmaxf(mx8[j], pv);
            sm8[j] += pv;
        }
    }
    float mx = mx8[0], sm = sm8[0];
#pragma unroll
    for (int j = 1; j < 8; ++j) { mx = fmaxf(mx, mx8[j]); sm += sm8[j]; }
    if ((lane & 7) == 0) M[(b * 8 + h) * Lc + q] = mx - sm * (1.0f / 2048.0f);
}

// ---------------- k_topk: radix-select top-40 (set-equivalent to stable top_k) ---
__global__ __launch_bounds__(256) void k_topk(const float* __restrict__ M, int* __restrict__ top,
                                              uint32_t* __restrict__ gmask) {
    __shared__ uint32_t hist[256];
    __shared__ uint32_t sh_bin, sh_need;
    __shared__ int sel[NUc];
    __shared__ int tie[128];
    __shared__ uint32_t selCnt, tieCnt;
    int bh = blockIdx.x;
    int t = threadIdx.x;
    uint32_t uk[8];
#pragma unroll
    for (int i = 0; i < 8; ++i) {
        uint32_t s = __float_as_uint(M[bh * Lc + i * 256 + t]);
        uk[i] = (s & 0x80000000u) ? ~s : (s | 0x80000000u);  // monotonic key
    }
    uint32_t prefix = 0, need = NUc;
    for (int pass = 0; pass < 4; ++pass) {
        int shift = 24 - 8 * pass;
        hist[t] = 0;
        __syncthreads();
#pragma unroll
        for (int i = 0; i < 8; ++i) {
            bool ok = (pass == 0) || ((uk[i] >> (shift + 8)) == prefix);
            if (ok) atomicAdd(&hist[(uk[i] >> shift) & 255u], 1u);
        }
        __syncthreads();
        if (t < 64) {  // single-wave suffix scan: lane l covers bins 4l..4l+3
            uint32_t c0 = hist[4 * t], c1 = hist[4 * t + 1];
            uint32_t c2 = hist[4 * t + 2], c3 = hist[4 * t + 3];
            uint32_t s = c0 + c1 + c2 + c3;
            uint32_t suf = s;
#pragma unroll
            for (int m = 1; m < 64; m <<= 1) {
                uint32_t o = __shfl_down(suf, m, 64);
                if (t + m < 64) suf += o;
            }
            uint32_t above = suf - s;
            if (suf >= need && above < need) {  // crossing lane
                uint32_t rem = need - above;
                uint32_t bsel, cnt;
                if (c3 >= rem) { bsel = 4 * t + 3; cnt = rem; }
                else if (c3 + c2 >= rem) { bsel = 4 * t + 2; cnt = rem - c3; }
                else if (c3 + c2 + c1 >= rem) { bsel = 4 * t + 1; cnt = rem - c3 - c2; }
                else { bsel = 4 * t; cnt = rem - c3 - c2 - c1; }
                sh_bin = bsel;
                sh_need = cnt;
            }
        }
        __syncthreads();
        prefix = (pass == 0) ? sh_bin : ((prefix << 8) | sh_bin);
        need = sh_need;
        __syncthreads();
    }
    const uint32_t T = prefix;
    if (t == 0) { selCnt = 0; tieCnt = 0; }
    __syncthreads();
#pragma unroll
    for (int i = 0; i < 8; ++i) {
        int idx = i * 256 + t;
        if (uk[i] > T) {
            uint32_t slot = atomicAdd(&selCnt, 1u);
            if (slot < NUc) sel[slot] = idx;
        } else if (uk[i] == T) {
            uint32_t slot = atomicAdd(&tieCnt, 1u);
            if (slot < 128) tie[slot] = idx;
        }
    }
    __syncthreads();
    if (t == 0) {  // take `need` smallest tie indices (stable top-k semantics)
        int n = (int)tieCnt;
        if (n > 128) n = 128;
        for (int a = 1; a < n; ++a) {
            int key = tie[a], c = a - 1;
            while (c >= 0 && tie[c] > key) { tie[c + 1] = tie[c]; --c; }
            tie[c + 1] = key;
        }
        uint32_t base = selCnt;
        for (uint32_t j = 0; j < need && base + j < NUc; ++j) sel[base + j] = tie[j];
    }
    __syncthreads();
    if (t < NUc) top[bh * NUc + t] = sel[t];
    if (t < 64) {
        uint32_t word = 0;
#pragma unroll
        for (int j = 0; j < NUc; ++j) {
            int s = sel[j];
            if ((s >> 5) == t) word |= 1u << (s & 31);
        }
        gmask[bh * 64 + t] = word;
    }
}

// ---------------- attention partials: 256-thread block = (bh, chunk) -------------
// 1024 blocks; wave w owns u-tile w. K-slice LDS-staged once (4-segment pattern);
// V read once per block, coalesced. V-mean accumulated via atomicAdd (wave 0).
__global__ __launch_bounds__(256, 4) void k_attn_part(const float* __restrict__ Q,
                                                      const float* __restrict__ K,
                                                      const float* __restrict__ V,
                                                      const int* __restrict__ top,
                                                      float* __restrict__ wsO,
                                                      float* __restrict__ wsm,
                                                      float* __restrict__ wsl,
                                                      float* __restrict__ vm) {
    __shared__ float Qs[40][64];     // 10.25 KB
    __shared__ float Ks[64][68];     // 17.4 KB (stride 68: conflict-free b128 reads)
    __shared__ float pT[4][64][12];  // 12.3 KB (48B rows: float4-aligned, bcast reads)
    __shared__ int tqs[40];
    int blk = blockIdx.x;            // xcd-affine: 8 XCD x 4 bh x 32 chunk
    int xcd = blk & 7, local = blk >> 3;
    int bh = xcd * 4 + (local >> 5);
    int chunk = local & 31;
    int b = bh >> 3, h = bh & 7;
    int t = threadIdx.x, w = t >> 6, lane = t & 63;

    if (t < 40) tqs[t] = top[bh * NUc + t];
    __syncthreads();
    for (int i = t; i < 40 * 64; i += 256) {
        int u = i >> 6, d = i & 63;
        Qs[u][d] = Q[(((size_t)(b * Lc + tqs[u])) * Hc + h) * Dc + d];
    }
    // stage K chunk h-slice: 64 rows x 64 floats; 16 lanes cover one row's 256 B
    // -> 4 contiguous segments per wave-instruction (vs 64 with thread-owns-row).
    const float* Kbase = K + (((size_t)(b * Lc + chunk * CHK)) * Hc + h) * Dc;
    for (int f = t; f < 1024; f += 256) {
        int r = f >> 4, c = f & 15;
        *reinterpret_cast<float4*>(&Ks[r][c * 4]) =
            *reinterpret_cast<const float4*>(Kbase + (size_t)r * 512 + c * 4);
    }
    __syncthreads();

    // scores: wave w, thread lane = key; acc[u] = dot(Q[w*10+u], K[key]) / 8
    float acc[UT];
#pragma unroll
    for (int u = 0; u < UT; ++u) acc[u] = 0.f;
#pragma unroll
    for (int i = 0; i < 16; ++i) {
        float4 kv = *reinterpret_cast<const float4*>(&Ks[lane][i * 4]);
#pragma unroll
        for (int u = 0; u < UT; ++u) {
            float4 qv = *reinterpret_cast<const float4*>(&Qs[w * UT + u][i * 4]);
            acc[u] += qv.x * kv.x + qv.y * kv.y + qv.z * kv.z + qv.w * kv.w;
        }
    }
#pragma unroll
    for (int u = 0; u < UT; ++u) acc[u] *= 0.125f;
    float mr[UT];
#pragma unroll
    for (int u = 0; u < UT; ++u) {
        float v = acc[u];
#pragma unroll
        for (int m = 1; m < 64; m <<= 1) v = fmaxf(v, __shfl_xor(v, m, 64));
        mr[u] = v;
    }
    float pr[UT];
#pragma unroll
    for (int u = 0; u < UT; ++u) {
        pr[u] = __expf(acc[u] - mr[u]);
        pT[w][lane][u] = pr[u];
    }
    float sr[UT];
#pragma unroll
    for (int u = 0; u < UT; ++u) {
        float v = pr[u];
#pragma unroll
        for (int m = 1; m < 64; m <<= 1) v += __shfl_xor(v, m, 64);
        sr[u] = v;
    }
    int sbase = (bh * NCH + chunk) * NUc + w * UT;
#pragma unroll
    for (int u = 0; u < UT; ++u) {
        if (lane == u) {
            wsm[sbase + u] = mr[u];
            wsl[sbase + u] = sr[u];
        }
    }
    // PV over the 64 keys: lane = d; V row reads are 256 B contiguous (coalesced).
    // pT reads are wave-uniform broadcasts; same-wave write->read needs no barrier.
#pragma unroll
    for (int u = 0; u < UT; ++u) acc[u] = 0.f;
    float vs = 0.f;
    const float* Vbh = V + ((size_t)b * Lc * Hc + h) * Dc;
    for (int k = 0; k < 64; ++k) {
        float vv = Vbh[(size_t)(chunk * CHK + k) * 512 + lane];
        vs += vv;
        float4 pa = *reinterpret_cast<const float4*>(&pT[w][k][0]);
        float4 pb = *reinterpret_cast<const float4*>(&pT[w][k][4]);
        float2 pc = *reinterpret_cast<const float2*>(&pT[w][k][8]);
        acc[0] += pa.x * vv; acc[1] += pa.y * vv; acc[2] += pa.z * vv; acc[3] += pa.w * vv;
        acc[4] += pb.x * vv; acc[5] += pb.y * vv; acc[6] += pb.z * vv; acc[7] += pb.w * vv;
        acc[8] += pc.x * vv; acc[9] += pc.y * vv;
    }
    if (w == 0) atomicAdd(&vm[bh * 64 + lane], vs * (1.0f / 2048.0f));
    size_t obase = (size_t)(bh * NCH + chunk) * 2560 + (size_t)(w * UT) * 64;
#pragma unroll
    for (int u = 0; u < UT; ++u) wsO[obase + u * 64 + lane] = acc[u];
}

// ---------------- Path A: fused output with inline 32-chunk combine --------------
__global__ void k_out_inl(const float* __restrict__ wsO, const float* __restrict__ wsm,
                          const float* __restrict__ wsl, const float* __restrict__ vm,
                          const int* __restrict__ top, const uint32_t* __restrict__ gmask,
                          float* __restrict__ out) {
    int o4 = blockIdx.x * blockDim.x + threadIdx.x;  // over 1M float4
    if (o4 >= Bc * Lc * Hc * (Dc / 4)) return;
    int dq = o4 & 15;
    int h = (o4 >> 4) & 7;
    int bl = o4 >> 7;
    int b = bl >> 11, l = bl & 2047;
    int bh = b * 8 + h;
    float4 v;
    uint32_t wmask = gmask[bh * 64 + (l >> 5)];
    if ((wmask >> (l & 31)) & 1u) {
        int u = 0;
#pragma unroll
        for (int j = 0; j < NUc; ++j)
            if (top[bh * NUc + j] == l) u = j;
        float cf[NCH];
        float m = -INFINITY;
#pragma unroll
        for (int c = 0; c < NCH; ++c) {
            cf[c] = wsm[(bh * NCH + c) * NUc + u];
            m = fmaxf(m, cf[c]);
        }
        float L = 0.f;
#pragma unroll
        for (int c = 0; c < NCH; ++c) {
            float e = __expf(cf[c] - m);
            L += wsl[(bh * NCH + c) * NUc + u] * e;
            cf[c] = e;
        }
        const float4* W4 = reinterpret_cast<const float4*>(wsO);
        float4 a = make_float4(0.f, 0.f, 0.f, 0.f);
#pragma unroll
        for (int c = 0; c < NCH; ++c) {
            float4 o = W4[(size_t)(bh * NCH + c) * 640 + u * 16 + dq];
            a.x += o.x * cf[c]; a.y += o.y * cf[c]; a.z += o.z * cf[c]; a.w += o.w * cf[c];
        }
        float inv = 1.0f / L;
        v = make_float4(a.x * inv, a.y * inv, a.z * inv, a.w * inv);
    } else {
        v = reinterpret_cast<const float4*>(vm)[bh * 16 + dq];
    }
    reinterpret_cast<float4*>(out)[o4] = v;
}

// ---------------- Path B fallback: comb (stats only) + staged out ----------------
__global__ __launch_bounds__(256) void k_comb(const float* __restrict__ wsO,
                                              const float* __restrict__ wsm,
                                              const float* __restrict__ wsl,
                                              float* __restrict__ stage) {
    __shared__ float cm[NCH][5], cl[NCH][5], cf[NCH][5];
    int blk = blockIdx.x;  // bh*8 + ut
    int ut = blk & 7, bh = blk >> 3;
    int t = threadIdx.x;
    for (int i = t; i < NCH * 5; i += 256) {
        int c = i / 5, j = i % 5;
        cm[c][j] = wsm[(bh * NCH + c) * NUc + ut * 5 + j];
        cl[c][j] = wsl[(bh * NCH + c) * NUc + ut * 5 + j];
    }
    __syncthreads();
    if (t < 5) {
        float m = -INFINITY;
#pragma unroll
        for (int c = 0; c < NCH; ++c) m = fmaxf(m, cm[c][t]);
        float L = 0.f;
#pragma unroll
        for (int c = 0; c < NCH; ++c) {
            float f = __expf(cm[c][t] - m);
            L += cl[c][t] * f;
            cf[c][t] = f;
        }
        float inv = 1.0f / L;
#pragma unroll
        for (int c = 0; c < NCH; ++c) cf[c][t] *= inv;
    }
    __syncthreads();
    for (int i = t; i < 5 * 64; i += 256) {
        int j = i >> 6, d = i & 63;
        float val = 0.f;
#pragma unroll
        for (int c = 0; c < NCH; ++c)
            val += wsO[((size_t)(bh * NCH + c)) * 2560 + (ut * 5 + j) * 64 + d] * cf[c][j];
        stage[(size_t)bh * 2560 + (ut * 5 + j) * 64 + d] = val;
    }
}

__global__ void k_out(const float* __restrict__ stage, const float* __restrict__ vm,
                      const int* __restrict__ top, const uint32_t* __restrict__ gmask,
                      float* __restrict__ out) {
    int o4 = blockIdx.x * blockDim.x + threadIdx.x;
    if (o4 >= Bc * Lc * Hc * (Dc / 4)) return;
    int dq = o4 & 15;
    int h = (o4 >> 4) & 7;
    int bl = o4 >> 7;
    int b = bl >> 11, l = bl & 2047;
    int bh = b * 8 + h;
    float4 v;
    uint32_t wmask = gmask[bh * 64 + (l >> 5)];
    if ((wmask >> (l & 31)) & 1u) {
        int u = 0;
#pragma unroll
        for (int j = 0; j < NUc; ++j)
            if (top[bh * NUc + j] == l) u = j;
        v = reinterpret_cast<const float4*>(stage)[(bh * NUc + u) * 16 + dq];
    } else {
        v = reinterpret_cast<const float4*>(vm)[bh * 16 + dq];
    }
    reinterpret_cast<float4*>(out)[o4] = v;
}

extern "C" void kernel_launch(void* const* d_in, const int* in_sizes, int n_in,
                              void* d_out, int out_size, void* d_ws, size_t ws_size,
                              hipStream_t stream) {
    (void)in_sizes; (void)n_in; (void)out_size;
    const float* Q = (const float*)d_in[0];
    const float* K = (const float*)d_in[1];
    const float* V = (const float*)d_in[2];
    float* out = (float*)d_out;

    int*      top   = (int*)d_ws;                          // 6.4 KB (pad to 8K)
    float*    vm    = (float*)((char*)d_ws + 8192);        // 8 KB
    uint32_t* gmask = (uint32_t*)((char*)d_ws + 16384);    // 8 KB
    float* M = (float*)((char*)d_out + 11075584);          // 256 KB (high in d_out)

    const bool bigws = ws_size >= 11534336;  // deterministic per-harness

    if (bigws) {
        // Path A: partials in d_ws -> no comb kernel, k_out combines inline.
        float* wsm = (float*)((char*)d_ws + 32768);        // 160 KB
        float* wsl = (float*)((char*)d_ws + 196608);       // 160 KB
        float* wsO = (float*)((char*)d_ws + 393216);       // 10.49 MB
        hipLaunchKernelGGL(k_M, dim3(2048), dim3(256), 0, stream, Q, K, M, vm);
        hipLaunchKernelGGL(k_topk, dim3(Bc * Hc), dim3(256), 0, stream, M, top, gmask);
        hipLaunchKernelGGL(k_attn_part, dim3(1024), dim3(256), 0, stream, Q, K, V, top,
                           wsO, wsm, wsl, vm);
        hipLaunchKernelGGL(k_out_inl, dim3(4096), dim3(256), 0, stream, wsO, wsm, wsl, vm,
                           top, gmask, out);
    } else {
        // Path B: partials in d_out, staged combine (race-free vs out writes).
        float* wsO   = (float*)d_out;                      // 10.49 MB
        float* wsm   = (float*)((char*)d_out + 10485760);  // 160 KB
        float* wsl   = (float*)((char*)d_out + 10649600);  // 160 KB
        float* stage = (float*)((char*)d_ws + 24576);      // 320 KB
        hipLaunchKernelGGL(k_M, dim3(2048), dim3(256), 0, stream, Q, K, M, vm);
        hipLaunchKernelGGL(k_topk, dim3(Bc * Hc), dim3(256), 0, stream, M, top, gmask);
        hipLaunchKernelGGL(k_attn_part, dim3(1024), dim3(256), 0, stream, Q, K, V, top,
                           wsO, wsm, wsl, vm);
        hipLaunchKernelGGL(k_comb, dim3(Bc * Hc * 8), dim3(256), 0, stream, wsO, wsm, wsl,
                           stage);
        hipLaunchKernelGGL(k_out, dim3(4096), dim3(256), 0, stream, stage, vm, top, gmask,
                           out);
    }
}